// Round 15
// baseline (133.675 us; speedup 1.0000x reference)
//
#include <hip/hip_runtime.h>
#include <stdint.h>

#define RELU(v) ((v) > 0.0f ? (v) : 0.0f)

typedef unsigned long long u64;
typedef unsigned int u32;
typedef unsigned short u16;
typedef float f32x16 __attribute__((ext_vector_type(16)));
typedef short bf16x8 __attribute__((ext_vector_type(8)));

constexpr int FEAT = 256;
constexpr int EMB  = 64;

// per-wave staging: 32 rows x 260 u16 (520 B stride, 2-bank rotation) = 16640 B; block = 2 waves.
// xv f32 overlay [32][66] = 8448 B <= 16640.
constexpr int STG_ROW = 260;   // u16 per staged row
constexpr int WAVE_BYTES = 32 * STG_ROW * 2;   // 16640
constexpr int XV_ROW = 66;     // f32 per xv row

__device__ inline u16 bf16_trunc(float v) { return (u16)(__float_as_uint(v) >> 16); }

__device__ inline u32 score_key(float s) {
    u32 u = __float_as_uint(s);
    return (u & 0x80000000u) ? ~u : (u | 0x80000000u);   // order-preserving f32 -> u32
}

__device__ inline bf16x8 pack_bf16x8(float4 lo, float4 hi) {
    bf16x8 r;
    r[0] = (short)bf16_trunc(lo.x); r[1] = (short)bf16_trunc(lo.y);
    r[2] = (short)bf16_trunc(lo.z); r[3] = (short)bf16_trunc(lo.w);
    r[4] = (short)bf16_trunc(hi.x); r[5] = (short)bf16_trunc(hi.y);
    r[6] = (short)bf16_trunc(hi.z); r[7] = (short)bf16_trunc(hi.w);
    return r;
}

// ---------------- setup: block0 = precompute bias_eff ; block1 = pack weights ------------------
// B-frag pack for v_mfma_f32_32x32x16_bf16: lane l holds B[k = ks*16 + (l>>5)*8 + j][n = c*32 + (l&31)]
// wrawpk: 32 tuples (ks 0..15, c 0..1).  w1pk: 24 tuples (b 0..2 = {xv rows 0-63, hv 64-127,
// en 192-255}, ks 0..3, c 0..1), t = b*8 + ks*2 + c.
__global__ __launch_bounds__(1024) void setup_kernel(
    const float* __restrict__ h, const int* __restrict__ idx_targets, int nT,
    const float* __restrict__ W_raw, const float* __restrict__ W1, const float* __restrict__ b1,
    float* __restrict__ bias_eff, u16* __restrict__ wrawpk, u16* __restrict__ w1pk)
{
    const int tid = threadIdx.x;
    if (blockIdx.x == 1) {   // ---- pack
        for (int i = tid; i < 56 * 64; i += 1024) {
            int tup  = i >> 6;
            int lane = i & 63;
            int n32  = lane & 31;
            int koff = (lane >> 5) * 8;
            if (tup < 32) {
                int ks = tup >> 1, c = tup & 1;
                int n = c * 32 + n32;
                #pragma unroll
                for (int j = 0; j < 8; ++j) {
                    int k = ks * 16 + koff + j;
                    wrawpk[(size_t)i * 8 + j] = bf16_trunc(W_raw[(size_t)k * EMB + n]);
                }
            } else {
                int tt = tup - 32;
                int b = tt >> 3, ks = (tt >> 1) & 3, c = tt & 1;
                int base = (b == 0) ? 0 : (b == 1 ? 64 : 192);
                int n = c * 32 + n32;
                #pragma unroll
                for (int j = 0; j < 8; ++j) {
                    int k = base + ks * 16 + koff + j;
                    w1pk[(size_t)(i - 32 * 64) * 8 + j] = bf16_trunc(W1[(size_t)k * EMB + n]);
                }
            }
        }
        return;
    }
    // ---- precompute bias_eff = b1 + relu(mean(h[idx_targets])) @ W1[128:192]
    __shared__ int   idx_s[1024];
    __shared__ float partial[16][64];
    __shared__ float hT[64];
    const int nid = nT > 1024 ? 1024 : nT;
    for (int i = tid; i < nid; i += 1024) idx_s[i] = idx_targets[i];
    __syncthreads();
    const int d = tid & 63, grp = tid >> 6;
    float s = 0.f;
    for (int t = grp; t < nid; t += 16)
        s += h[(size_t)idx_s[t] * EMB + d];
    partial[grp][d] = s;
    __syncthreads();
    if (tid < 64) {
        float m = 0.f;
        #pragma unroll
        for (int g = 0; g < 16; ++g) m += partial[g][tid];
        hT[tid] = RELU(m / (float)nT);
    }
    __syncthreads();
    if (tid < 64) {
        float acc = b1[tid];
        #pragma unroll 8
        for (int dd = 0; dd < 64; ++dd)
            acc = fmaf(hT[dd], W1[(size_t)(128 + dd) * EMB + tid], acc);
        bias_eff[tid] = acc;
    }
}

// ---------------- approx scores via bf16 32x32x16 MFMA (prefilter only) ------------------------
// Block = 2 waves (128 thr); wave owns 32 e-rows x 64 cols (2 col-tiles of 32).
// A-frag: lane l: row = l&31, k = ks*16 + (l>>5)*8 + j.  C: col = c*32 + (l&31),
// row = (reg&3) + 8*(reg>>2) + 4*(l>>5)  [guide-verified].  All LDS wave-local -> no barriers.
// Per k-step one B-frag feeds 32 rows (2x fewer B loads + MFMAs per row than 16x16).
__global__ __launch_bounds__(128, 2) void approx_score_kernel(
    const float* __restrict__ x, const float* __restrict__ h,
    const float* __restrict__ degree, const float* __restrict__ beta,
    const int* __restrict__ exp_nodes,
    const u16* __restrict__ wrawpk, const u16* __restrict__ w1pk,
    const float* __restrict__ b_raw,
    const float* __restrict__ W_num, const float* __restrict__ b_num,
    const float* __restrict__ W2, const float* __restrict__ bias_eff,
    u64* __restrict__ pairs, int E)
{
    __shared__ __align__(16) unsigned char smem[2][WAVE_BYTES];   // 33280 B

    const int tid   = threadIdx.x;
    const int wid   = tid >> 6;
    const int lane  = tid & 63;
    const int row32 = lane & 31;
    const int kh    = lane >> 5;          // k-half 0..1
    const int tileBase = blockIdx.x * 64;

    const int grow = tileBase + wid * 32 + row32;
    const int node = exp_nodes[grow < E ? grow : 0];
    const float* hrow = h + (size_t)node * EMB;
    const float dg = degree[node];
    const float bt = beta[node];

    u16*   stg = (u16*)&smem[wid][0];
    float* xvp = (float*)&smem[wid][0];

    // ---- stage 32 x-rows (coalesced 1KB/instr), bf16 into LDS, 4 batches of 8 in flight
    #pragma unroll
    for (int bch = 0; bch < 4; ++bch) {
        float4 v0, v1, v2, v3, v4, v5, v6, v7;
        {
            int r = bch * 8;
            v0 = *reinterpret_cast<const float4*>(x + (size_t)__shfl(node, r + 0) * FEAT + lane * 4);
            v1 = *reinterpret_cast<const float4*>(x + (size_t)__shfl(node, r + 1) * FEAT + lane * 4);
            v2 = *reinterpret_cast<const float4*>(x + (size_t)__shfl(node, r + 2) * FEAT + lane * 4);
            v3 = *reinterpret_cast<const float4*>(x + (size_t)__shfl(node, r + 3) * FEAT + lane * 4);
            v4 = *reinterpret_cast<const float4*>(x + (size_t)__shfl(node, r + 4) * FEAT + lane * 4);
            v5 = *reinterpret_cast<const float4*>(x + (size_t)__shfl(node, r + 5) * FEAT + lane * 4);
            v6 = *reinterpret_cast<const float4*>(x + (size_t)__shfl(node, r + 6) * FEAT + lane * 4);
            v7 = *reinterpret_cast<const float4*>(x + (size_t)__shfl(node, r + 7) * FEAT + lane * 4);
        }
        #define STG_WRITE(rr, vv) { \
            ushort4 pk; pk.x = bf16_trunc(vv.x); pk.y = bf16_trunc(vv.y); \
            pk.z = bf16_trunc(vv.z); pk.w = bf16_trunc(vv.w); \
            *reinterpret_cast<ushort4*>(stg + (bch * 8 + rr) * STG_ROW + lane * 4) = pk; }
        STG_WRITE(0, v0) STG_WRITE(1, v1) STG_WRITE(2, v2) STG_WRITE(3, v3)
        STG_WRITE(4, v4) STG_WRITE(5, v5) STG_WRITE(6, v6) STG_WRITE(7, v7)
        #undef STG_WRITE
    }
    __builtin_amdgcn_wave_barrier();   // staging writes before fragment reads (wave-local)

    // ---- GEMM 1: xv = x @ W_raw + b_raw   (16 k-steps x 2 col-tiles)
    f32x16 acc1[2];
    #pragma unroll
    for (int c = 0; c < 2; ++c) {
        float bv = b_raw[c * 32 + row32];
        #pragma unroll
        for (int r = 0; r < 16; ++r) acc1[c][r] = bv;
    }
    #pragma unroll
    for (int ks = 0; ks < 16; ++ks) {
        bf16x8 a = *reinterpret_cast<const bf16x8*>(stg + row32 * STG_ROW + ks * 16 + kh * 8);
        #pragma unroll
        for (int c = 0; c < 2; ++c) {
            bf16x8 b = *reinterpret_cast<const bf16x8*>(wrawpk + (size_t)((ks * 2 + c) * 64 + lane) * 8);
            acc1[c] = __builtin_amdgcn_mfma_f32_32x32x16_bf16(a, b, acc1[c], 0, 0, 0);
        }
    }
    __builtin_amdgcn_wave_barrier();   // fragment reads before xv overlay writes

    // relu(xv) -> f32 overlay [row][col], row stride 66 f32
    #pragma unroll
    for (int c = 0; c < 2; ++c)
        #pragma unroll
        for (int r = 0; r < 16; ++r) {
            int row = (r & 3) + 8 * (r >> 2) + 4 * kh;
            xvp[row * XV_ROW + c * 32 + row32] = RELU(acc1[c][r]);
        }
    __builtin_amdgcn_wave_barrier();   // xv writes before xv fragment reads

    // ---- GEMM 2 (h_T folded into bias_eff): xv, hv, en blocks, 4 k-steps x 2 col-tiles each
    f32x16 acc2[2];
    #pragma unroll
    for (int c = 0; c < 2; ++c) {
        float bv = bias_eff[c * 32 + row32];
        #pragma unroll
        for (int r = 0; r < 16; ++r) acc2[c][r] = bv;
    }

    // xv block (w1pk tuples 0..7)
    #pragma unroll
    for (int ks = 0; ks < 4; ++ks) {
        const float* xp = xvp + row32 * XV_ROW + ks * 16 + kh * 8;
        float4 lo = *reinterpret_cast<const float4*>(xp);
        float4 hi = *reinterpret_cast<const float4*>(xp + 4);
        bf16x8 a = pack_bf16x8(lo, hi);
        #pragma unroll
        for (int c = 0; c < 2; ++c) {
            bf16x8 b = *reinterpret_cast<const bf16x8*>(w1pk + (size_t)((ks * 2 + c) * 64 + lane) * 8);
            acc2[c] = __builtin_amdgcn_mfma_f32_32x32x16_bf16(a, b, acc2[c], 0, 0, 0);
        }
    }

    // hv block (w1pk tuples 8..15): gathered h row, per-lane 32B per k-step
    #pragma unroll
    for (int ks = 0; ks < 4; ++ks) {
        const float* hp = hrow + ks * 16 + kh * 8;
        float4 lo = *reinterpret_cast<const float4*>(hp);
        float4 hi = *reinterpret_cast<const float4*>(hp + 4);
        lo.x = RELU(lo.x); lo.y = RELU(lo.y); lo.z = RELU(lo.z); lo.w = RELU(lo.w);
        hi.x = RELU(hi.x); hi.y = RELU(hi.y); hi.z = RELU(hi.z); hi.w = RELU(hi.w);
        bf16x8 a = pack_bf16x8(lo, hi);
        #pragma unroll
        for (int c = 0; c < 2; ++c) {
            bf16x8 b = *reinterpret_cast<const bf16x8*>(w1pk + (size_t)((8 + ks * 2 + c) * 64 + lane) * 8);
            acc2[c] = __builtin_amdgcn_mfma_f32_32x32x16_bf16(a, b, acc2[c], 0, 0, 0);
        }
    }

    // en block (w1pk tuples 16..23): numerics computed in-register
    #pragma unroll
    for (int ks = 0; ks < 4; ++ks) {
        bf16x8 a;
        #pragma unroll
        for (int j = 0; j < 8; ++j) {
            int k = ks * 16 + kh * 8 + j;
            float v = RELU(fmaf(dg, W_num[k], fmaf(bt, W_num[EMB + k], b_num[k])));
            a[j] = (short)bf16_trunc(v);
        }
        #pragma unroll
        for (int c = 0; c < 2; ++c) {
            bf16x8 b = *reinterpret_cast<const bf16x8*>(w1pk + (size_t)((16 + ks * 2 + c) * 64 + lane) * 8);
            acc2[c] = __builtin_amdgcn_mfma_f32_32x32x16_bf16(a, b, acc2[c], 0, 0, 0);
        }
    }

    // score: p[reg] = sum_c relu(hid) * W2[col]; reduce over the 32 cols (lanes within k-half)
    float w2a = W2[row32], w2b = W2[32 + row32];
    float p[16];
    #pragma unroll
    for (int r = 0; r < 16; ++r)
        p[r] = RELU(acc2[0][r]) * w2a + RELU(acc2[1][r]) * w2b;
    #pragma unroll
    for (int m = 1; m < 32; m <<= 1) {
        #pragma unroll
        for (int r = 0; r < 16; ++r) p[r] += __shfl_xor(p[r], m);
    }
    if (row32 == 0) {   // lanes 0 (kh=0) and 32 (kh=1) emit their 16 rows
        #pragma unroll
        for (int r = 0; r < 16; ++r) {
            int row = (r & 3) + 8 * (r >> 2) + 4 * kh;
            int g = tileBase + wid * 32 + row;
            if (g < E)
                pairs[g] = ((u64)score_key(p[r]) << 32) | (u32)(~(u32)g);
        }
    }
}

// ---------------- bitonic helper --------------------------------------------------------------
template<int N, int NT>
__device__ inline void bitonic_desc(u64* s, int tid) {
    for (int k = 2; k <= N; k <<= 1) {
        for (int j = k >> 1; j > 0; j >>= 1) {
            __syncthreads();
            for (int i = tid; i < N; i += NT) {
                int ixj = i ^ j;
                if (ixj > i) {
                    u64 a = s[i], b = s[ixj];
                    bool sw = ((i & k) == 0) ? (a < b) : (a > b);
                    if (sw) { s[i] = b; s[ixj] = a; }
                }
            }
        }
    }
    __syncthreads();
}

template<int N, int NT, int KEEP>
__global__ __launch_bounds__(NT) void seg_sort_kernel(
    const u64* __restrict__ in, int n_in, int seg, u64* __restrict__ out)
{
    __shared__ u64 s[N];
    int tid = threadIdx.x;
    int base = blockIdx.x * seg;
    for (int i = tid; i < N; i += NT) {
        int g = base + i;
        s[i] = (i < seg && g < n_in) ? in[g] : 0ULL;
    }
    bitonic_desc<N, NT>(s, tid);
    if (tid < KEEP) out[blockIdx.x * KEEP + tid] = s[tid];
}

// ---------------- exact f32 rescore (1 row per wave; r11-proven body) --------------------------
__global__ __launch_bounds__(256) void rescore_kernel(
    const float* __restrict__ x, const float* __restrict__ h,
    const float* __restrict__ degree, const float* __restrict__ beta,
    const int* __restrict__ exp_nodes,
    const float* __restrict__ W_raw, const float* __restrict__ b_raw,
    const float* __restrict__ W_num, const float* __restrict__ b_num,
    const float* __restrict__ W1, const float* __restrict__ W2,
    const float* __restrict__ bias_eff,
    const u64* __restrict__ cand, u64* __restrict__ pairs2, int E)
{
    __shared__ float emb[4][192];
    const int tid = threadIdx.x;
    const int wid = tid >> 6;
    const int c   = tid & 63;
    const int i   = blockIdx.x * 4 + wid;

    const u64 raw = cand[i];
    const u32 low = (u32)raw;
    const u32 ge  = ~low;
    const int node = (raw != 0ULL && ge < (u32)E) ? exp_nodes[ge] : 0;

    const float* xrow = x + (size_t)node * FEAT;

    float s0 = b_raw[c], s1 = 0.f, s2 = 0.f, s3 = 0.f;
    for (int k = 0; k < FEAT; k += 4) {
        s0 = fmaf(xrow[k + 0], W_raw[(size_t)(k + 0) * EMB + c], s0);
        s1 = fmaf(xrow[k + 1], W_raw[(size_t)(k + 1) * EMB + c], s1);
        s2 = fmaf(xrow[k + 2], W_raw[(size_t)(k + 2) * EMB + c], s2);
        s3 = fmaf(xrow[k + 3], W_raw[(size_t)(k + 3) * EMB + c], s3);
    }
    float xv = (s0 + s1) + (s2 + s3);

    emb[wid][c]       = RELU(xv);
    emb[wid][64 + c]  = RELU(h[(size_t)node * EMB + c]);
    emb[wid][128 + c] = RELU(fmaf(degree[node], W_num[c], fmaf(beta[node], W_num[EMB + c], b_num[c])));
    __syncthreads();

    float h0 = bias_eff[c], h1 = 0.f, h2 = 0.f, h3 = 0.f;
    for (int j = 0; j < 64; j += 2) {
        h0 = fmaf(emb[wid][j],     W1[(size_t)j * EMB + c],       h0);
        h1 = fmaf(emb[wid][j + 1], W1[(size_t)(j + 1) * EMB + c], h1);
    }
    for (int j = 0; j < 64; j += 2) {
        h2 = fmaf(emb[wid][64 + j],     W1[(size_t)(64 + j) * EMB + c],     h2);
        h3 = fmaf(emb[wid][64 + j + 1], W1[(size_t)(64 + j + 1) * EMB + c], h3);
    }
    for (int j = 0; j < 64; j += 2) {
        h0 = fmaf(emb[wid][128 + j],     W1[(size_t)(192 + j) * EMB + c],     h0);
        h1 = fmaf(emb[wid][128 + j + 1], W1[(size_t)(192 + j + 1) * EMB + c], h1);
    }
    float hid = (h0 + h1) + (h2 + h3);

    float p = RELU(hid) * W2[c];
    #pragma unroll
    for (int m = 1; m < 64; m <<= 1) p += __shfl_xor(p, m);

    if (c == 0)
        pairs2[i] = (raw == 0ULL) ? 0ULL : (((u64)score_key(p) << 32) | low);
}

// ---------------- final: sort 1024 exact survivors, emit top-128 (r13/r14-proven) --------------
__global__ __launch_bounds__(1024) void topk_final_kernel(
    const u64* __restrict__ in,
    const int* __restrict__ exp_nodes, float* __restrict__ out)
{
    __shared__ u64 s[1024];
    int tid = threadIdx.x;
    s[tid] = in[tid];
    bitonic_desc<1024, 1024>(s, tid);
    if (tid < 128) {
        u64 p = s[tid];
        u32 idx = ~(u32)(p & 0xFFFFFFFFu);
        out[tid]       = 1.0f;                   // candidates (straight-through fwd == 1.0)
        out[128 + tid] = (float)exp_nodes[idx];  // cand_indices (exact in f32: < 2^24)
    }
}

extern "C" void kernel_launch(void* const* d_in, const int* in_sizes, int n_in,
                              void* d_out, int out_size, void* d_ws, size_t ws_size,
                              hipStream_t stream) {
    const float* x          = (const float*)d_in[0];
    const float* h          = (const float*)d_in[1];
    const float* degree     = (const float*)d_in[2];
    const float* beta       = (const float*)d_in[3];
    const int*   exp_nodes  = (const int*)d_in[4];
    const int*   idx_targets= (const int*)d_in[5];
    const float* W_raw      = (const float*)d_in[6];
    const float* b_raw      = (const float*)d_in[7];
    const float* W_num      = (const float*)d_in[8];
    const float* b_num      = (const float*)d_in[9];
    const float* W1         = (const float*)d_in[10];
    const float* b1         = (const float*)d_in[11];
    const float* W2         = (const float*)d_in[12];
    // b2 / temperature / epsilon: order-invariant, unused

    int E  = in_sizes[4];
    int nT = in_sizes[5];

    char* ws = (char*)d_ws;
    float* bias_eff = (float*)ws;                          // 256 B
    u16* wrawpk = (u16*)(ws + 256);                        // 32 KB
    u16* w1pk   = (u16*)(ws + 256 + 32768);                // 24 KB (32 KB slot)
    u64* pairs  = (u64*)(ws + 256 + 65536);                // E u64
    size_t pairs_bytes = (((size_t)E * 8) + 255) / 256 * 256;
    u64* cand1  = (u64*)(ws + 256 + 65536 + pairs_bytes);            // 32768 u64 (256 KB)
    u64* cand2  = (u64*)(ws + 256 + 65536 + pairs_bytes + 262144);   // 1024 u64
    u64* pairs2 = (u64*)(ws + 256 + 65536 + pairs_bytes + 262144 + 8192);  // 1024 u64

    // 1) setup: precompute (block 0) || pack (block 1)
    setup_kernel<<<2, 1024, 0, stream>>>(h, idx_targets, nT, W_raw, W1, b1,
                                         bias_eff, wrawpk, w1pk);

    // 2) approx scores (bf16 32x32x16 MFMA prefilter, 2-wave blocks, 64 rows/block)
    int nTiles = (E + 63) / 64;
    approx_score_kernel<<<nTiles, 128, 0, stream>>>(x, h, degree, beta, exp_nodes,
                                                    wrawpk, w1pk, b_raw, W_num, b_num,
                                                    W2, bias_eff, pairs, E);

    // 3) stage 1: 128 segments (<=1024 each), keep approx-top-256 -> 32768
    int seg1 = (E + 127) / 128;
    seg_sort_kernel<1024, 512, 256><<<128, 512, 0, stream>>>(pairs, E, seg1, cand1);

    // 4) stage 2: 32 blocks of 1024, keep approx-top-32 -> 1024 candidates
    seg_sort_kernel<1024, 512, 32><<<32, 512, 0, stream>>>(cand1, 32768, 1024, cand2);

    // 5) exact f32 rescore of 1024 candidates, 1 row/wave (r11-proven body)
    rescore_kernel<<<256, 256, 0, stream>>>(x, h, degree, beta, exp_nodes,
                                            W_raw, b_raw, W_num, b_num, W1, W2,
                                            bias_eff, cand2, pairs2, E);

    // 6) final: sort 1024 exact pairs, emit top-128
    topk_final_kernel<<<1, 1024, 0, stream>>>(pairs2, exp_nodes, (float*)d_out);
}